// Round 1
// baseline (5296.594 us; speedup 1.0000x reference)
//
#include <hip/hip_runtime.h>

#define CH     64
#define TSEQ   4096
#define TOUT   2048
#define NBLK   4
#define NBATCH 256
#define TT     122          // output timesteps per tile
#define HALO   6            // 4 blocks shrink + 1 col for dilated + 1 spare
#define COLS   128          // TT + HALO, exactly 2 cols per lane
#define NTILE  34           // ceil(4096/122)
#define QPT    61           // dilated outputs per tile (TT/2)

// workspace layout (float offsets)
#define WT_OFF   0          // [4][c][h][4] = sig_k0,sig_k1,gate_k0,gate_k1
#define OWT_OFF  65536      // [4][h][c]
#define DWT_OFF  81920      // [ci][co][2]
#define SWT_OFF  90112      // [c][o]
#define DIL_TOTAL 33554432LL

__global__ void prep_weights(const float* __restrict__ sig_w, const float* __restrict__ gate_w,
                             const float* __restrict__ out_w, const float* __restrict__ dil_w,
                             const float* __restrict__ skip_w, float* __restrict__ ws) {
  int idx = blockIdx.x * 256 + threadIdx.x;
  if (idx < NBLK * CH * CH) {
    int i = idx >> 12, h = (idx >> 6) & 63, c = idx & 63;
    int src = ((i * CH + h) * CH + c) * 2;
    float* wt = ws + WT_OFF + (((i * CH + c) * CH) + h) * 4;
    wt[0] = sig_w[src];  wt[1] = sig_w[src + 1];
    wt[2] = gate_w[src]; wt[3] = gate_w[src + 1];
    ws[OWT_OFF + (i * CH + h) * CH + c] = out_w[(i * CH + c) * CH + h];
  }
  if (idx < CH * CH) {
    int co = idx >> 6, ci = idx & 63;
    ws[DWT_OFF + (ci * CH + co) * 2 + 0] = dil_w[(co * CH + ci) * 2 + 0];
    ws[DWT_OFF + (ci * CH + co) * 2 + 1] = dil_w[(co * CH + ci) * 2 + 1];
    ws[SWT_OFF + ci * CH + co]           = skip_w[co * CH + ci];
  }
}

__global__ __launch_bounds__(256, 2)
void wavenet_fused(const float* __restrict__ x,
                   const float* __restrict__ sig_b, const float* __restrict__ gate_b,
                   const float* __restrict__ out_b, const float* __restrict__ skip_b,
                   const float* __restrict__ dil_b, const float* __restrict__ ws,
                   float* __restrict__ out) {
  __shared__ float gT[CH * COLS];    // residual state, [c][p]
  __shared__ float sgT[CH * COLS];   // relu(sig)*sigmoid(gate), [h][p]

  const int tile = blockIdx.x % NTILE;
  const int b    = blockIdx.x / NTILE;
  const int t0   = tile * TT;
  const int tid  = threadIdx.x;
  const int lane = tid & 63;
  const int wv   = __builtin_amdgcn_readfirstlane(tid >> 6);  // wave id (uniform)
  const int p0   = lane * 2;                                  // this lane's 2 columns
  const int h0   = wv * 16;                                   // phase-A h strip
  const int c0   = wv * 16;                                   // phase-B/C c strip

  // ---- load x tile; global index t0-HALO+p, zeros outside [0,T) (causal pad) ----
  for (int idx = tid; idx < CH * COLS; idx += 256) {
    int p = idx & (COLS - 1);
    int tg = t0 - HALO + p;
    float v = 0.f;
    if (tg >= 0 && tg < TSEQ) v = x[(b * CH + (idx >> 7)) * TSEQ + tg];
    gT[idx] = v;
  }
  __syncthreads();

  for (int blk = 0; blk < NBLK; ++blk) {
    // ---- phase A: sg[h,p] = relu(sig conv) * sigmoid(gate conv) ----
    float2 aS[16], aG[16];
#pragma unroll
    for (int j = 0; j < 16; ++j) { aS[j] = make_float2(0.f, 0.f); aG[j] = make_float2(0.f, 0.f); }
#pragma unroll 2
    for (int c = 0; c < CH; ++c) {
      const float2 gc = *(const float2*)&gT[c * COLS + p0];
      const float  gp = __shfl_up(gc.y, 1, 64);   // g[c, p0-1]; lane0 garbage -> col 0 never used
      const float* wb = ws + WT_OFF + ((blk * CH + c) * CH + h0) * 4;  // uniform -> s_load
#pragma unroll
      for (int j = 0; j < 16; ++j) {
        const float w0 = wb[j*4+0], w1 = wb[j*4+1], w2 = wb[j*4+2], w3 = wb[j*4+3];
        aS[j].x = fmaf(w0, gp,   fmaf(w1, gc.x, aS[j].x));
        aS[j].y = fmaf(w0, gc.x, fmaf(w1, gc.y, aS[j].y));
        aG[j].x = fmaf(w2, gp,   fmaf(w3, gc.x, aG[j].x));
        aG[j].y = fmaf(w2, gc.x, fmaf(w3, gc.y, aG[j].y));
      }
    }
#pragma unroll
    for (int j = 0; j < 16; ++j) {
      const int h = h0 + j;
      const float bs = sig_b[blk * CH + h], bg = gate_b[blk * CH + h];
      const float sx = fmaxf(aS[j].x + bs, 0.f);
      const float sy = fmaxf(aS[j].y + bs, 0.f);
      const float qx = sx * __builtin_amdgcn_rcpf(1.f + __expf(-(aG[j].x + bg)));
      const float qy = sy * __builtin_amdgcn_rcpf(1.f + __expf(-(aG[j].y + bg)));
      *(float2*)&sgT[h * COLS + p0] = make_float2(qx, qy);
    }
    __syncthreads();

    // ---- phase B: g[c,p] += out_b[c] + sum_h ow[c,h]*sg[h,p] ----
    float2 acc[16];
#pragma unroll
    for (int j = 0; j < 16; ++j) { const float ob = out_b[blk * CH + c0 + j]; acc[j] = make_float2(ob, ob); }
#pragma unroll 2
    for (int h = 0; h < CH; ++h) {
      const float2 sv = *(const float2*)&sgT[h * COLS + p0];
      const float* wb = ws + OWT_OFF + (blk * CH + h) * CH + c0;  // uniform -> s_load
#pragma unroll
      for (int j = 0; j < 16; ++j) {
        acc[j].x = fmaf(wb[j], sv.x, acc[j].x);
        acc[j].y = fmaf(wb[j], sv.y, acc[j].y);
      }
    }
    // g_i valid for p >= blk+1; tile 0 keeps p<HALO pinned to 0 (causal zero pad)
    const int lo = (tile == 0) ? HALO : (blk + 1);
#pragma unroll
    for (int j = 0; j < 16; ++j) {
      const int base = (c0 + j) * COLS;
      if (p0     >= lo) gT[base + p0]     += acc[j].x;
      if (p0 + 1 >= lo) gT[base + p0 + 1] += acc[j].y;
    }
    __syncthreads();
  }

  // ---- dilated stride-2 conv: y[co,tau] = db + sum_c dw0*g[2tau-1] + dw1*g[2tau] ----
  const int q   = lane;
  const int tau = tile * QPT + q;
  const bool act = (q < QPT) && (tau < TOUT);
  const int pp  = act ? (2 * q + 5) : 5;   // local col of g[2tau-1]
  float ad[16];
#pragma unroll
  for (int j = 0; j < 16; ++j) ad[j] = dil_b[c0 + j];
  for (int c = 0; c < CH; ++c) {
    const float ga = gT[c * COLS + pp];
    const float gb = gT[c * COLS + pp + 1];
    const float* wb = ws + DWT_OFF + (c * CH + c0) * 2;  // uniform -> s_load
#pragma unroll
    for (int j = 0; j < 16; ++j)
      ad[j] = fmaf(wb[2*j], ga, fmaf(wb[2*j+1], gb, ad[j]));
  }
  if (act) {
#pragma unroll
    for (int j = 0; j < 16; ++j)
      out[(long long)(b * CH + c0 + j) * TOUT + tau] = ad[j];
  }

  // ---- skip: 1x1 conv on final timestep, owned by the last tile, wave 0 ----
  if (tile == NTILE - 1 && wv == 0) {
    const int o = lane;
    const int plast = (TSEQ - 1) - t0 + HALO;   // = 75
    float a = skip_b[o];
    for (int c = 0; c < CH; ++c)
      a = fmaf(ws[SWT_OFF + c * CH + o], gT[c * COLS + plast], a);
    out[DIL_TOTAL + b * CH + o] = a;
  }
}

extern "C" void kernel_launch(void* const* d_in, const int* in_sizes, int n_in,
                              void* d_out, int out_size, void* d_ws, size_t ws_size,
                              hipStream_t stream) {
  const float* x      = (const float*)d_in[0];
  const float* sig_w  = (const float*)d_in[1];
  const float* sig_b  = (const float*)d_in[2];
  const float* gate_w = (const float*)d_in[3];
  const float* gate_b = (const float*)d_in[4];
  const float* out_w  = (const float*)d_in[5];
  const float* out_b  = (const float*)d_in[6];
  const float* skip_w = (const float*)d_in[7];
  const float* skip_b = (const float*)d_in[8];
  const float* dil_w  = (const float*)d_in[9];
  const float* dil_b  = (const float*)d_in[10];
  float* ws  = (float*)d_ws;    // needs 94208 floats = 368 KB of scratch
  float* out = (float*)d_out;

  prep_weights<<<dim3(64), dim3(256), 0, stream>>>(sig_w, gate_w, out_w, dil_w, skip_w, ws);
  wavenet_fused<<<dim3(NBATCH * NTILE), dim3(256), 0, stream>>>(
      x, sig_b, gate_b, out_b, skip_b, dil_b, (const float*)ws, out);
}

// Round 2
// 1199.903 us; speedup vs baseline: 4.4142x; 4.4142x over previous
//
#include <hip/hip_runtime.h>

typedef short s16x8 __attribute__((ext_vector_type(8)));
typedef short s16x4 __attribute__((ext_vector_type(4)));
typedef float f32x4 __attribute__((ext_vector_type(4)));

#define CH 64
#define TSEQ 4096
#define TOUT 2048
#define NBLK 4
#define COLS 112          // columns per tile (7 n-tiles of 16)
#define TT 106            // owned output timesteps per tile
#define HALO 6
#define NTILE 39          // ceil(4096/106)
#define NT 7              // n-tiles
#define GBROW 72          // bf16 row stride: 144B, 16B-aligned, 36 dw = 4 mod 32 -> uniform banks
#define GFROW 68          // fp32 row stride: 272B, 16B-aligned, 68 dw = 4 mod 32
#define QPT 53            // dilated outputs per tile
#define DIL_TOTAL 33554432

// d_ws layout: shorts (bf16) then floats
#define WA_OFF 0          // [blk4][mat2][half2][kc2][tap2][h64][c-chunk32] bf16
#define WO_OFF 131072     // [blk4][half2][kc2][c64][h-chunk32]
#define WD_OFF 163840     // [half2][kc2][tap2][co64][ci-chunk32]
#define SK_BYTE_OFF 360448 // fp32 [ci64][o64]

__device__ __forceinline__ short f2bf(float x) {     // RNE fp32->bf16
  unsigned u = __float_as_uint(x);
  return (short)((u + 0x7fffu + ((u >> 16) & 1u)) >> 16);
}
__device__ __forceinline__ float bf2f(short h) {
  return __uint_as_float(((unsigned)(unsigned short)h) << 16);
}
__device__ __forceinline__ f32x4 mfma16(s16x8 a, s16x8 b, f32x4 c) {
  return __builtin_amdgcn_mfma_f32_16x16x32_bf16(a, b, c, 0, 0, 0);
}

__global__ void prep(const float* __restrict__ sig_w, const float* __restrict__ gate_w,
                     const float* __restrict__ out_w, const float* __restrict__ dil_w,
                     const float* __restrict__ skip_w, short* __restrict__ wsS,
                     float* __restrict__ wsF) {
  const int idx = blockIdx.x * 256 + threadIdx.x;
  if (idx < 131072) {                       // WA: sig/gate conv weights
    const int inner = idx & 2047, grp = idx >> 11;
    const int tap = grp & 1, kc = (grp >> 1) & 1, half = (grp >> 2) & 1;
    const int mat = (grp >> 3) & 1, blk = grp >> 4;
    const int h = inner >> 5, c = kc * 32 + (inner & 31);
    const float* W = mat ? gate_w : sig_w;
    const float w = W[((blk * CH + h) * CH + c) * 2 + tap];
    const short hi = f2bf(w);
    wsS[WA_OFF + idx] = half ? f2bf(w - bf2f(hi)) : hi;
  } else if (idx < 163840) {                // WO: 1x1 out conv
    const int i2 = idx - 131072;
    const int inner = i2 & 2047, grp = i2 >> 11;
    const int kc = grp & 1, half = (grp >> 1) & 1, blk = grp >> 2;
    const int c = inner >> 5, h = kc * 32 + (inner & 31);
    const float w = out_w[(blk * CH + c) * CH + h];
    const short hi = f2bf(w);
    wsS[idx] = half ? f2bf(w - bf2f(hi)) : hi;
  } else if (idx < 180224) {                // WD: dilated conv
    const int i3 = idx - 163840;
    const int inner = i3 & 2047, grp = i3 >> 11;
    const int tap = grp & 1, kc = (grp >> 1) & 1, half = (grp >> 2) & 1;
    const int co = inner >> 5, ci = kc * 32 + (inner & 31);
    const float w = dil_w[(co * CH + ci) * 2 + tap];
    const short hi = f2bf(w);
    wsS[idx] = half ? f2bf(w - bf2f(hi)) : hi;
  } else if (idx < 184320) {                // SK: skip weights, fp32 transposed
    const int i4 = idx - 180224;
    const int ci = i4 >> 6, o = i4 & 63;
    wsF[i4] = skip_w[o * CH + ci];
  }
}

__global__ __launch_bounds__(256, 2)
void wavenet_mfma(const float* __restrict__ x,
                  const float* __restrict__ sig_b, const float* __restrict__ gate_b,
                  const float* __restrict__ out_b, const float* __restrict__ skip_b,
                  const float* __restrict__ dil_b, const short* __restrict__ wsS,
                  const float* __restrict__ wsF, float* __restrict__ out) {
  __shared__ __align__(16) float gF[COLS * GFROW];        // fp32 residual master [p][c]
  __shared__ __align__(16) short GBs[2 * 113 * GBROW];    // bf16 hi/lo [half][r=p+1][c]; shared with U

  const int tile = blockIdx.x % NTILE;
  const int b    = blockIdx.x / NTILE;
  const int t0   = tile * TT;
  const int tid  = threadIdx.x;
  const int lane = tid & 63;
  const int wv   = tid >> 6;
  const int n    = lane & 15;          // n / D-col index
  const int g4   = lane >> 4;          // quad id
  const int hbase = wv * 16;           // this wave's m-strip

  // ---- x -> gF (fp32) + GB (bf16 hi/lo), causal zero-pad outside [0,T) ----
  for (int idx = tid; idx < CH * COLS; idx += 256) {
    const int c = idx / COLS, p = idx - c * COLS;
    const int tg = t0 - HALO + p;
    float v = 0.f;
    if (tg >= 0 && tg < TSEQ) v = x[(b * CH + c) * TSEQ + tg];
    gF[p * GFROW + c] = v;
    const short hi = f2bf(v);
    GBs[(p + 1) * GBROW + c] = hi;
    GBs[(113 + p + 1) * GBROW + c] = f2bf(v - bf2f(hi));
  }
  if (tid < 2 * GBROW) {               // row 0 = p=-1 (zero pad)
    const int half = tid / GBROW;
    GBs[half * 113 * GBROW + (tid - half * GBROW)] = 0;
  }
  __syncthreads();

  // B-fragment base pointers: row = n + tap (+ n-tile/kc via immediates)
  const short* bpH0 = &GBs[(n + 0) * GBROW + g4 * 8];
  const short* bpH1 = &GBs[(n + 1) * GBROW + g4 * 8];
  const short* bpL0 = &GBs[(113 + n + 0) * GBROW + g4 * 8];
  const short* bpL1 = &GBs[(113 + n + 1) * GBROW + g4 * 8];
  const int lo_p = (tile == 0) ? HALO : 0;   // tile 0 keeps t<0 columns pinned to 0
  const int lbase = (hbase + n) * 32 + g4 * 8;   // A-frag lane offset

#pragma unroll 1
  for (int blk = 0; blk < NBLK; ++blk) {
    // ---- A-fragments (weights) from prepped global, frag-ordered ----
    s16x8 wS[2][2][2], wG[2][2][2], wO2[2][2];   // [half][kc][tap] / [half][kc]
#pragma unroll
    for (int half = 0; half < 2; ++half)
#pragma unroll
      for (int kc = 0; kc < 2; ++kc) {
#pragma unroll
        for (int tap = 0; tap < 2; ++tap) {
          wS[half][kc][tap] = *(const s16x8*)&wsS[WA_OFF + ((((blk*2+0)*2+half)*2+kc)*2+tap)*2048 + lbase];
          wG[half][kc][tap] = *(const s16x8*)&wsS[WA_OFF + ((((blk*2+1)*2+half)*2+kc)*2+tap)*2048 + lbase];
        }
        wO2[half][kc] = *(const s16x8*)&wsS[WO_OFF + ((blk*2+half)*2+kc)*2048 + lbase];
      }

    // ---- GEMM1: S,T[h=16-strip][p] via split-bf16 (HH + LH + HL) ----
    f32x4 aS[NT], aG[NT];
#pragma unroll
    for (int j = 0; j < NT; ++j) { aS[j] = (f32x4)0.f; aG[j] = (f32x4)0.f; }
#pragma unroll
    for (int j = 0; j < NT; ++j) {
      const int ro = j * 16 * GBROW;
#pragma unroll
      for (int kc = 0; kc < 2; ++kc) {
        const int co = ro + kc * 32;
        {
          const s16x8 bh = *(const s16x8*)(bpH0 + co);
          const s16x8 bl = *(const s16x8*)(bpL0 + co);
          aS[j] = mfma16(wS[0][kc][0], bh, aS[j]);
          aS[j] = mfma16(wS[1][kc][0], bh, aS[j]);
          aS[j] = mfma16(wS[0][kc][0], bl, aS[j]);
          aG[j] = mfma16(wG[0][kc][0], bh, aG[j]);
          aG[j] = mfma16(wG[1][kc][0], bh, aG[j]);
          aG[j] = mfma16(wG[0][kc][0], bl, aG[j]);
        }
        {
          const s16x8 bh = *(const s16x8*)(bpH1 + co);
          const s16x8 bl = *(const s16x8*)(bpL1 + co);
          aS[j] = mfma16(wS[0][kc][1], bh, aS[j]);
          aS[j] = mfma16(wS[1][kc][1], bh, aS[j]);
          aS[j] = mfma16(wS[0][kc][1], bl, aS[j]);
          aG[j] = mfma16(wG[0][kc][1], bh, aG[j]);
          aG[j] = mfma16(wG[1][kc][1], bh, aG[j]);
          aG[j] = mfma16(wG[0][kc][1], bl, aG[j]);
        }
      }
    }
    __syncthreads();   // GEMM1 reads of GB done

    // ---- elementwise: U = relu(S+bs)*sigmoid(T+bg); write U hi/lo over GB ----
    const f32x4 bs4 = *(const f32x4*)(sig_b  + blk * 64 + hbase + g4 * 4);
    const f32x4 bg4 = *(const f32x4*)(gate_b + blk * 64 + hbase + g4 * 4);
#pragma unroll
    for (int j = 0; j < NT; ++j) {
      s16x4 uh, ul;
#pragma unroll
      for (int r = 0; r < 4; ++r) {
        const float s = fmaxf(aS[j][r] + bs4[r], 0.f);
        const float t = aG[j][r] + bg4[r];
        const float u = s * __builtin_amdgcn_rcpf(1.f + __expf(-t));
        const short hi = f2bf(u);
        uh[r] = hi; ul[r] = f2bf(u - bf2f(hi));
      }
      const int r1 = j * 16 + n + 1;
      *(s16x4*)&GBs[r1 * GBROW + hbase + g4 * 4] = uh;
      *(s16x4*)&GBs[(113 + r1) * GBROW + hbase + g4 * 4] = ul;
    }
    __syncthreads();   // U complete

    // ---- GEMM2: dG[c=16-strip][p] = b_out + Wout * U ----
    f32x4 aO[NT];
    const f32x4 ob4 = *(const f32x4*)(out_b + blk * 64 + hbase + g4 * 4);
#pragma unroll
    for (int j = 0; j < NT; ++j) aO[j] = ob4;
#pragma unroll
    for (int j = 0; j < NT; ++j) {
      const int ro = j * 16 * GBROW;
#pragma unroll
      for (int kc = 0; kc < 2; ++kc) {
        const s16x8 uh = *(const s16x8*)(bpH1 + ro + kc * 32);
        const s16x8 ul = *(const s16x8*)(bpL1 + ro + kc * 32);
        aO[j] = mfma16(wO2[0][kc], uh, aO[j]);
        aO[j] = mfma16(wO2[1][kc], uh, aO[j]);
        aO[j] = mfma16(wO2[0][kc], ul, aO[j]);
      }
    }
    __syncthreads();   // GEMM2 reads of U done

    // ---- epilogue: residual update in fp32 + re-split into GB ----
#pragma unroll
    for (int j = 0; j < NT; ++j) {
      const int p = j * 16 + n;
      float* gp = &gF[p * GFROW + hbase + g4 * 4];
      const f32x4 old = *(const f32x4*)gp;
      const f32x4 nv = (p >= lo_p) ? (old + aO[j]) : old;
      *(f32x4*)gp = nv;
      s16x4 nh, nl;
#pragma unroll
      for (int r = 0; r < 4; ++r) {
        const short hi = f2bf(nv[r]);
        nh[r] = hi; nl[r] = f2bf(nv[r] - bf2f(hi));
      }
      *(s16x4*)&GBs[(p + 1) * GBROW + hbase + g4 * 4] = nh;
      *(s16x4*)&GBs[(113 + p + 1) * GBROW + hbase + g4 * 4] = nl;
    }
    __syncthreads();
  }

  // ---- dilated stride-2 conv (GEMM over tau) ----
  {
    s16x8 wD[2][2][2];
#pragma unroll
    for (int half = 0; half < 2; ++half)
#pragma unroll
      for (int kc = 0; kc < 2; ++kc)
#pragma unroll
        for (int tap = 0; tap < 2; ++tap)
          wD[half][kc][tap] = *(const s16x8*)&wsS[WD_OFF + ((half*2+kc)*2+tap)*2048 + lbase];
    const f32x4 db4 = *(const f32x4*)(dil_b + hbase + g4 * 4);
    const int tau0 = tile * QPT;
#pragma unroll
    for (int j = 0; j < 4; ++j) {
      const int idx = j * 16 + n;
      const int idxc = (idx < QPT) ? idx : (QPT - 1);   // clamp reads; stores masked
      f32x4 ad = db4;
      const int rbase = (6 + idxc * 2) * GBROW + g4 * 8;
#pragma unroll
      for (int kc = 0; kc < 2; ++kc)
#pragma unroll
        for (int tap = 0; tap < 2; ++tap) {
          const s16x8 bh = *(const s16x8*)&GBs[rbase + tap * GBROW + kc * 32];
          const s16x8 bl = *(const s16x8*)&GBs[113 * GBROW + rbase + tap * GBROW + kc * 32];
          ad = mfma16(wD[0][kc][tap], bh, ad);
          ad = mfma16(wD[1][kc][tap], bh, ad);
          ad = mfma16(wD[0][kc][tap], bl, ad);
        }
      const int tau = tau0 + idx;
      if (idx < QPT && tau < TOUT) {
        const int cobase = b * CH + hbase + g4 * 4;
#pragma unroll
        for (int r = 0; r < 4; ++r)
          out[(cobase + r) * TOUT + tau] = ad[r];
      }
    }
  }

  // ---- skip: 1x1 conv on t=4095, exact fp32 from gF ----
  if (tile == NTILE - 1 && wv == 0) {
    const int o = lane;
    float a = skip_b[o];
    for (int c = 0; c < CH; ++c)
      a = fmaf(wsF[c * CH + o], gF[73 * GFROW + c], a);   // p(4095) = 4095-4028+6 = 73
    out[DIL_TOTAL + b * CH + o] = a;
  }
}

extern "C" void kernel_launch(void* const* d_in, const int* in_sizes, int n_in,
                              void* d_out, int out_size, void* d_ws, size_t ws_size,
                              hipStream_t stream) {
  const float* x      = (const float*)d_in[0];
  const float* sig_w  = (const float*)d_in[1];
  const float* sig_b  = (const float*)d_in[2];
  const float* gate_w = (const float*)d_in[3];
  const float* gate_b = (const float*)d_in[4];
  const float* out_w  = (const float*)d_in[5];
  const float* out_b  = (const float*)d_in[6];
  const float* skip_w = (const float*)d_in[7];
  const float* skip_b = (const float*)d_in[8];
  const float* dil_w  = (const float*)d_in[9];
  const float* dil_b  = (const float*)d_in[10];
  short* wsS = (short*)d_ws;
  float* wsF = (float*)((char*)d_ws + SK_BYTE_OFF);
  float* out = (float*)d_out;

  prep<<<dim3(720), dim3(256), 0, stream>>>(sig_w, gate_w, out_w, dil_w, skip_w, wsS, wsF);
  wavenet_mfma<<<dim3(256 * NTILE), dim3(256), 0, stream>>>(
      x, sig_b, gate_b, out_b, skip_b, dil_b, (const short*)wsS, (const float*)wsF, out);
}